// Round 1
// baseline (1123.119 us; speedup 1.0000x reference)
//
#include <hip/hip_runtime.h>
#include <cmath>

#define B_SZ 4096
#define N_SZ 8192
#define D_SZ 256
#define INV_TEMP 2.0f
#define EPS 1e-8f
#define IPB 8      // output rows per block in lse kernel
#define TPB 256

__device__ __forceinline__ const float* row_ptr(const float* zi, const float* zj, int r) {
    return r < B_SZ ? zi + (size_t)r * D_SZ : zj + (size_t)(r - B_SZ) * D_SZ;
}

// ---- Kernel A: inverse norms (one wave per row) ----
__global__ __launch_bounds__(256) void norms_kernel(const float* __restrict__ zi,
                                                    const float* __restrict__ zj,
                                                    float* __restrict__ inv_norm) {
    int wave = threadIdx.x >> 6;
    int lane = threadIdx.x & 63;
    int row = blockIdx.x * 4 + wave;
    if (row >= N_SZ) return;
    const float* src = row_ptr(zi, zj, row);
    float4 v = reinterpret_cast<const float4*>(src)[lane];   // 64 lanes x 4 = 256
    float ss = v.x * v.x + v.y * v.y + v.z * v.z + v.w * v.w;
    #pragma unroll
    for (int off = 32; off; off >>= 1) ss += __shfl_xor(ss, off, 64);
    if (lane == 0) inv_norm[row] = 1.0f / fmaxf(sqrtf(ss), EPS);
}

// ---- Kernel B: fused sim + online LSE + pos, 8 rows per block ----
__global__ __launch_bounds__(TPB) void lse_kernel(const float* __restrict__ zi,
                                                  const float* __restrict__ zj,
                                                  const float* __restrict__ inv_norm,
                                                  float* __restrict__ row_out) {
    __shared__ float zi_s[IPB][D_SZ];
    __shared__ float pm[IPB][TPB / 64], ps[IPB][TPB / 64], pp[IPB][TPB / 64];

    const int i0 = blockIdx.x * IPB;
    const int t = threadIdx.x;

    // Stage the block's 8 i-rows, pre-scaled by inv_norm[i]/TEMP.
    for (int k = t; k < IPB * D_SZ; k += TPB) {
        int ii = k >> 8;           // k / D_SZ
        int d  = k & (D_SZ - 1);   // k % D_SZ
        int gi = i0 + ii;
        zi_s[ii][d] = row_ptr(zi, zj, gi)[d] * inv_norm[gi] * INV_TEMP;
    }
    __syncthreads();

    float m[IPB], s[IPB], pos[IPB];
    #pragma unroll
    for (int ii = 0; ii < IPB; ++ii) { m[ii] = -1e30f; s[ii] = 0.0f; pos[ii] = 0.0f; }

    for (int j = t; j < N_SZ; j += TPB) {
        const float* zr = row_ptr(zi, zj, j);
        const float invn_j = inv_norm[j];
        float dot[IPB];
        #pragma unroll
        for (int ii = 0; ii < IPB; ++ii) dot[ii] = 0.0f;
        for (int d = 0; d < D_SZ; d += 4) {
            float4 v = *reinterpret_cast<const float4*>(zr + d);
            #pragma unroll
            for (int ii = 0; ii < IPB; ++ii) {
                dot[ii] += v.x * zi_s[ii][d]     + v.y * zi_s[ii][d + 1]
                         + v.z * zi_s[ii][d + 2] + v.w * zi_s[ii][d + 3];
            }
        }
        #pragma unroll
        for (int ii = 0; ii < IPB; ++ii) {
            const int gi = i0 + ii;
            const float sim = dot[ii] * invn_j;   // already includes 1/TEMP
            const int partner = gi < B_SZ ? gi + B_SZ : gi - B_SZ;
            if (j == partner) pos[ii] = sim;
            if (j != gi) {
                float mn = fmaxf(m[ii], sim);
                s[ii] = s[ii] * __expf(m[ii] - mn) + __expf(sim - mn);
                m[ii] = mn;
            }
        }
    }

    // Wave-level butterfly reduce (m,s) and sum pos.
    #pragma unroll
    for (int ii = 0; ii < IPB; ++ii) {
        #pragma unroll
        for (int off = 32; off; off >>= 1) {
            float mo = __shfl_xor(m[ii], off, 64);
            float so = __shfl_xor(s[ii], off, 64);
            float po = __shfl_xor(pos[ii], off, 64);
            float mn = fmaxf(m[ii], mo);
            s[ii] = s[ii] * __expf(m[ii] - mn) + so * __expf(mo - mn);
            m[ii] = mn;
            pos[ii] += po;
        }
    }
    const int wave = t >> 6, lane = t & 63;
    if (lane == 0) {
        #pragma unroll
        for (int ii = 0; ii < IPB; ++ii) {
            pm[ii][wave] = m[ii]; ps[ii][wave] = s[ii]; pp[ii][wave] = pos[ii];
        }
    }
    __syncthreads();
    if (t < IPB) {
        float mm = -1e30f, ssum = 0.0f, ppos = 0.0f;
        #pragma unroll
        for (int w = 0; w < TPB / 64; ++w) {
            float mo = pm[t][w], so = ps[t][w];
            float mn = fmaxf(mm, mo);
            ssum = ssum * __expf(mm - mn) + so * __expf(mo - mn);
            mm = mn;
            ppos += pp[t][w];
        }
        row_out[i0 + t] = mm + logf(ssum) - ppos;   // lse_i - pos_i
    }
}

// ---- Kernel C: final sum / N ----
__global__ __launch_bounds__(256) void final_reduce(const float* __restrict__ row_out,
                                                    float* __restrict__ out) {
    float acc = 0.0f;
    for (int i = threadIdx.x; i < N_SZ; i += 256) acc += row_out[i];
    #pragma unroll
    for (int off = 32; off; off >>= 1) acc += __shfl_xor(acc, off, 64);
    __shared__ float w[4];
    if ((threadIdx.x & 63) == 0) w[threadIdx.x >> 6] = acc;
    __syncthreads();
    if (threadIdx.x == 0) out[0] = (w[0] + w[1] + w[2] + w[3]) / (float)N_SZ;
}

extern "C" void kernel_launch(void* const* d_in, const int* in_sizes, int n_in,
                              void* d_out, int out_size, void* d_ws, size_t ws_size,
                              hipStream_t stream) {
    const float* zi = (const float*)d_in[0];
    const float* zj = (const float*)d_in[1];
    float* inv_norm = (float*)d_ws;            // 8192 floats
    float* row_out  = inv_norm + N_SZ;         // 8192 floats
    float* out = (float*)d_out;

    norms_kernel<<<N_SZ / 4, 256, 0, stream>>>(zi, zj, inv_norm);
    lse_kernel<<<N_SZ / IPB, TPB, 0, stream>>>(zi, zj, inv_norm, row_out);
    final_reduce<<<1, 256, 0, stream>>>(row_out, out);
}

// Round 2
// 120.988 us; speedup vs baseline: 9.2829x; 9.2829x over previous
//
#include <hip/hip_runtime.h>
#include <hip/hip_bf16.h>
#include <cmath>

#define B_SZ 4096
#define N_SZ 8192
#define D_SZ 256
#define EPS 1e-8f

typedef __attribute__((ext_vector_type(8))) short s16x8;   // 8 bf16 (4 VGPRs)
typedef __attribute__((ext_vector_type(4))) float f32x4;   // MFMA C/D

__device__ __forceinline__ unsigned short f2bf(float f) {
    __hip_bfloat16 b = __float2bfloat16(f);
    return *reinterpret_cast<unsigned short*>(&b);
}

// ---- Kernel 1: inv_norm (fp32) + normalized bf16 matrix ZN [N][D] ----
__global__ __launch_bounds__(256) void prep_kernel(const float* __restrict__ zi,
                                                   const float* __restrict__ zj,
                                                   unsigned short* __restrict__ zn,
                                                   float* __restrict__ inv_norm) {
    const int wave = threadIdx.x >> 6, lane = threadIdx.x & 63;
    const int row = blockIdx.x * 4 + wave;
    const float* src = row < B_SZ ? zi + (size_t)row * D_SZ
                                  : zj + (size_t)(row - B_SZ) * D_SZ;
    float4 v = reinterpret_cast<const float4*>(src)[lane];
    float ss = v.x * v.x + v.y * v.y + v.z * v.z + v.w * v.w;
    #pragma unroll
    for (int off = 32; off; off >>= 1) ss += __shfl_xor(ss, off, 64);
    const float invn = 1.0f / fmaxf(sqrtf(ss), EPS);
    if (lane == 0) inv_norm[row] = invn;
    ushort4 o;
    o.x = f2bf(v.x * invn); o.y = f2bf(v.y * invn);
    o.z = f2bf(v.z * invn); o.w = f2bf(v.w * invn);
    *reinterpret_cast<ushort4*>(zn + (size_t)row * D_SZ + lane * 4) = o;
}

// ---- Kernel 2: pos[i] = dot(z_i, z_{i+B}) * invn_i * invn_{i+B} * 2  (fp32 exact) ----
__global__ __launch_bounds__(256) void pos_kernel(const float* __restrict__ zi,
                                                  const float* __restrict__ zj,
                                                  const float* __restrict__ inv_norm,
                                                  float* __restrict__ pos) {
    const int wave = threadIdx.x >> 6, lane = threadIdx.x & 63;
    const int i = blockIdx.x * 4 + wave;          // 0..B-1
    float4 a = reinterpret_cast<const float4*>(zi + (size_t)i * D_SZ)[lane];
    float4 b = reinterpret_cast<const float4*>(zj + (size_t)i * D_SZ)[lane];
    float d = a.x * b.x + a.y * b.y + a.z * b.z + a.w * b.w;
    #pragma unroll
    for (int off = 32; off; off >>= 1) d += __shfl_xor(d, off, 64);
    if (lane == 0) {
        float p = d * inv_norm[i] * inv_norm[i + B_SZ] * 2.0f;
        pos[i] = p;
        pos[i + B_SZ] = p;
    }
}

// ---- Kernel 3: fused sim-GEMM + fixed-base exp-sum ----
// Grid: 64 row-tiles x 8 j-chunks = 512 blocks, 256 thr (4 waves).
// Wave owns 32 rows (A in registers); B tiles 64x256 bf16 in LDS, double-buffered,
// XOR-swizzled (byte ^= (row&7)<<4) for conflict-free ds_read_b128.
__global__ __launch_bounds__(256) void simlse_kernel(const unsigned short* __restrict__ zn,
                                                     float* __restrict__ partial) {
    __shared__ char lds[2][32768];

    const int t = threadIdx.x;
    const int wave = t >> 6, lane = t & 63;
    const int rt = blockIdx.x >> 3;              // row tile 0..63
    const int chunk = blockIdx.x & 7;            // j chunk 0..7 (1024 cols each)
    const int i0 = rt * 128 + wave * 32;         // wave's first row
    const int j0base = chunk * 1024;

    const int rl = lane & 15;                    // row-in-frag / col-in-frag
    const int kg = lane >> 4;                    // k-subgroup
    const int xorv = (rl & 7) << 4;

    // A fragments: 2 rowgroups x 8 k-steps, held in registers for the whole kernel.
    s16x8 afrag[2][8];
    #pragma unroll
    for (int g = 0; g < 2; ++g) {
        const unsigned short* arow = zn + (size_t)(i0 + g * 16 + rl) * D_SZ;
        #pragma unroll
        for (int kk = 0; kk < 8; ++kk)
            afrag[g][kk] = *reinterpret_cast<const s16x8*>(arow + kk * 32 + kg * 8);
    }

    float s_acc[2][4];
    #pragma unroll
    for (int g = 0; g < 2; ++g)
        #pragma unroll
        for (int r = 0; r < 4; ++r) s_acc[g][r] = 0.0f;

    uint4 streg[8];

    #define STAGE_LOAD(JT)                                                        \
        {                                                                         \
            const char* gsrc = reinterpret_cast<const char*>(zn) +                \
                               (size_t)(j0base + (JT) * 64) * 512;                \
            _Pragma("unroll")                                                     \
            for (int p = 0; p < 8; ++p) {                                         \
                int slot = t + p * 256;                                           \
                int row = slot >> 5, cb = slot & 31;                              \
                streg[p] = *reinterpret_cast<const uint4*>(gsrc + row * 512 + cb * 16); \
            }                                                                     \
        }

    #define STAGE_WRITE(BUF)                                                      \
        {                                                                         \
            _Pragma("unroll")                                                     \
            for (int p = 0; p < 8; ++p) {                                         \
                int slot = t + p * 256;                                           \
                int row = slot >> 5, cb = slot & 31;                              \
                *reinterpret_cast<uint4*>((BUF) +                                 \
                    ((row * 512 + cb * 16) ^ ((row & 7) << 4))) = streg[p];       \
            }                                                                     \
        }

    #define COMPUTE(BUF)                                                          \
        {                                                                         \
            f32x4 acc[2][4];                                                      \
            _Pragma("unroll")                                                     \
            for (int g = 0; g < 2; ++g)                                           \
                _Pragma("unroll")                                                 \
                for (int f = 0; f < 4; ++f)                                       \
                    acc[g][f] = (f32x4){0.f, 0.f, 0.f, 0.f};                      \
            _Pragma("unroll")                                                     \
            for (int kk = 0; kk < 8; ++kk) {                                      \
                s16x8 bfrag[4];                                                   \
                _Pragma("unroll")                                                 \
                for (int f = 0; f < 4; ++f) {                                     \
                    int boff = ((f * 16 + rl) * 512 + kk * 64 + kg * 16) ^ xorv;  \
                    bfrag[f] = *reinterpret_cast<const s16x8*>((BUF) + boff);     \
                }                                                                 \
                _Pragma("unroll")                                                 \
                for (int g = 0; g < 2; ++g)                                       \
                    _Pragma("unroll")                                             \
                    for (int f = 0; f < 4; ++f)                                   \
                        acc[g][f] = __builtin_amdgcn_mfma_f32_16x16x32_bf16(      \
                            afrag[g][kk], bfrag[f], acc[g][f], 0, 0, 0);          \
            }                                                                     \
            _Pragma("unroll")                                                     \
            for (int g = 0; g < 2; ++g)                                           \
                _Pragma("unroll")                                                 \
                for (int f = 0; f < 4; ++f)                                       \
                    _Pragma("unroll")                                             \
                    for (int r = 0; r < 4; ++r)                                   \
                        s_acc[g][r] += __expf(fmaf(acc[g][f][r], 2.0f, -2.0f));   \
        }

    STAGE_LOAD(0);
    STAGE_WRITE(lds[0]);
    __syncthreads();

    for (int jt = 0; jt < 16; ++jt) {
        if (jt < 15) STAGE_LOAD(jt + 1);
        COMPUTE(lds[jt & 1]);
        __syncthreads();
        if (jt < 15) {
            STAGE_WRITE(lds[(jt + 1) & 1]);
            __syncthreads();
        }
    }

    // Reduce s over the 16 lanes of each k-group (cols), then write per-row partial.
    #pragma unroll
    for (int g = 0; g < 2; ++g) {
        #pragma unroll
        for (int r = 0; r < 4; ++r) {
            float v = s_acc[g][r];
            #pragma unroll
            for (int off = 1; off < 16; off <<= 1) v += __shfl_xor(v, off, 64);
            if (rl == 0)
                partial[chunk * N_SZ + i0 + g * 16 + kg * 4 + r] = v;
        }
    }
    #undef STAGE_LOAD
    #undef STAGE_WRITE
    #undef COMPUTE
}

// ---- Kernel 4: loss = sum_i (2 + log(sum_c partial - 1) - pos_i) / N ----
__global__ __launch_bounds__(256) void final_kernel(const float* __restrict__ partial,
                                                    const float* __restrict__ pos,
                                                    float* __restrict__ out) {
    float acc = 0.0f;
    for (int row = threadIdx.x; row < N_SZ; row += 256) {
        float s = -1.0f;                      // remove diagonal exp(2-2)=1
        #pragma unroll
        for (int c = 0; c < 8; ++c) s += partial[c * N_SZ + row];
        acc += 2.0f + logf(s) - pos[row];
    }
    #pragma unroll
    for (int off = 32; off; off >>= 1) acc += __shfl_xor(acc, off, 64);
    __shared__ float w[4];
    if ((threadIdx.x & 63) == 0) w[threadIdx.x >> 6] = acc;
    __syncthreads();
    if (threadIdx.x == 0) out[0] = (w[0] + w[1] + w[2] + w[3]) / (float)N_SZ;
}

extern "C" void kernel_launch(void* const* d_in, const int* in_sizes, int n_in,
                              void* d_out, int out_size, void* d_ws, size_t ws_size,
                              hipStream_t stream) {
    const float* zi = (const float*)d_in[0];
    const float* zj = (const float*)d_in[1];

    char* ws = (char*)d_ws;
    unsigned short* zn = (unsigned short*)ws;                 // 8192*256*2 = 4 MB
    float* inv_norm = (float*)(ws + 4194304);                 // 32 KB
    float* pos      = (float*)(ws + 4194304 + 32768);         // 32 KB
    float* partial  = (float*)(ws + 4194304 + 65536);         // 8*8192*4 = 256 KB
    float* out = (float*)d_out;

    prep_kernel<<<N_SZ / 4, 256, 0, stream>>>(zi, zj, zn, inv_norm);
    pos_kernel<<<B_SZ / 4, 256, 0, stream>>>(zi, zj, inv_norm, pos);
    simlse_kernel<<<512, 256, 0, stream>>>(zn, partial);
    final_kernel<<<1, 256, 0, stream>>>(partial, pos, out);
}

// Round 3
// 55.912 us; speedup vs baseline: 20.0874x; 2.1639x over previous
//
#include <hip/hip_runtime.h>
#include <hip/hip_bf16.h>
#include <cmath>

#define B_SZ 4096
#define N_SZ 8192
#define D_SZ 256
#define EPS 1e-8f
#define C_2LOG2E 2.8853900817779268f   // 2*log2(e): exp(2x-2)=exp2(fma(x,C,-C))

typedef __attribute__((ext_vector_type(8))) short s16x8;   // 8 bf16 (4 VGPRs)
typedef __attribute__((ext_vector_type(4))) float f32x4;   // MFMA C/D

__device__ __forceinline__ unsigned short f2bf(float f) {
    __hip_bfloat16 b = __float2bfloat16(f);
    return *reinterpret_cast<unsigned short*>(&b);
}

__device__ __forceinline__ void dma16(const void* g, void* l) {
    __builtin_amdgcn_global_load_lds(
        (const __attribute__((address_space(1))) unsigned int*)g,
        (__attribute__((address_space(3))) unsigned int*)l, 16, 0, 0);
}

// k-major panel layout: byte(row, col16B-slot) =
//   (row>>6)*32768 + slot*1024 + (row&63)*16      (slot = col_bf16/8, 0..31)

// ---- Kernel 1: norms + pos + bf16 k-major ZN. One wave per pair (i, i+B). ----
__global__ __launch_bounds__(256) void prep_kernel(const float* __restrict__ zi,
                                                   const float* __restrict__ zj,
                                                   char* __restrict__ znb,
                                                   float* __restrict__ pos) {
    const int wave = threadIdx.x >> 6, lane = threadIdx.x & 63;
    const int i = blockIdx.x * 4 + wave;               // 0..B-1
    float4 a = reinterpret_cast<const float4*>(zi + (size_t)i * D_SZ)[lane];
    float4 b = reinterpret_cast<const float4*>(zj + (size_t)i * D_SZ)[lane];
    float ssa = a.x * a.x + a.y * a.y + a.z * a.z + a.w * a.w;
    float ssb = b.x * b.x + b.y * b.y + b.z * b.z + b.w * b.w;
    float dab = a.x * b.x + a.y * b.y + a.z * b.z + a.w * b.w;
    #pragma unroll
    for (int off = 32; off; off >>= 1) {
        ssa += __shfl_xor(ssa, off, 64);
        ssb += __shfl_xor(ssb, off, 64);
        dab += __shfl_xor(dab, off, 64);
    }
    const float invna = 1.0f / fmaxf(sqrtf(ssa), EPS);
    const float invnb = 1.0f / fmaxf(sqrtf(ssb), EPS);
    if (lane == 0) {
        float p = dab * invna * invnb * 2.0f;
        pos[i] = p;
        pos[i + B_SZ] = p;
    }
    // row i (from zi) and row i+B (from zj), k-major, lane covers cols 4l..4l+3 (8B)
    const int slot = lane >> 1, half = (lane & 1) * 8;
    {
        ushort4 o; o.x = f2bf(a.x * invna); o.y = f2bf(a.y * invna);
                   o.z = f2bf(a.z * invna); o.w = f2bf(a.w * invna);
        char* p0 = znb + (size_t)(i >> 6) * 32768 + slot * 1024 + (i & 63) * 16 + half;
        *reinterpret_cast<ushort4*>(p0) = o;
    }
    {
        const int r = i + B_SZ;
        ushort4 o; o.x = f2bf(b.x * invnb); o.y = f2bf(b.y * invnb);
                   o.z = f2bf(b.z * invnb); o.w = f2bf(b.w * invnb);
        char* p0 = znb + (size_t)(r >> 6) * 32768 + slot * 1024 + (r & 63) * 16 + half;
        *reinterpret_cast<ushort4*>(p0) = o;
    }
}

// ---- Kernel 2: fused sim-GEMM + fixed-base exp-sum ----
// Grid: 32 row-tiles x 16 j-chunks = 512 blocks (2/CU), 256 thr (4 waves).
// Wave owns a 64-row A panel in registers (K=256 fully); B panels (64 rows x 256)
// staged 32KB linear via global_load_lds, double-buffered; reads conflict-free.
__global__ __launch_bounds__(256, 2) void simlse_kernel(const char* __restrict__ znb,
                                                        float* __restrict__ partial) {
    __shared__ __attribute__((aligned(16))) char lds[2][32768];

    const int t = threadIdx.x;
    const int wave = t >> 6, lane = t & 63;
    const int rt = blockIdx.x >> 4;              // row tile 0..31 (256 rows)
    const int chunk = blockIdx.x & 15;           // j chunk 0..15 (512 cols)
    const int rl = lane & 15;                    // A-row / B-col in fragment
    const int kg = lane >> 4;                    // k-subgroup (8 bf16 = 16B)
    const int i0 = (rt * 4 + wave) * 64;         // wave's first row

    // A panel: 4 rowgroups x 8 k-steps, registers for whole kernel (128 VGPRs).
    const char* ap = znb + (size_t)(rt * 4 + wave) * 32768;
    s16x8 afrag[4][8];
    #pragma unroll
    for (int g = 0; g < 4; ++g)
        #pragma unroll
        for (int kk = 0; kk < 8; ++kk)
            afrag[g][kk] = *reinterpret_cast<const s16x8*>(
                ap + ((kk * 4 + kg) * 64 + g * 16 + rl) * 16);

    float s_acc[4][4];
    #pragma unroll
    for (int g = 0; g < 4; ++g)
        #pragma unroll
        for (int r = 0; r < 4; ++r) s_acc[g][r] = 0.0f;

    // Linear 32KB panel copy: wave stages 8KB = 8 x 1KB DMA.
    #define STAGE(BUF, JT)                                                        \
        {                                                                         \
            const char* gp = znb + (size_t)(chunk * 8 + (JT)) * 32768 +           \
                             wave * 8192 + lane * 16;                             \
            char* lp = (BUF) + wave * 8192;                                       \
            _Pragma("unroll")                                                     \
            for (int c = 0; c < 8; ++c) dma16(gp + c * 1024, lp + c * 1024);      \
        }

    // f-outer keeps only acc[4] (16 regs) live; B frag read once per (f,kk).
    #define COMPUTE(BUF)                                                          \
        {                                                                         \
            _Pragma("unroll")                                                     \
            for (int f = 0; f < 4; ++f) {                                         \
                f32x4 acc[4];                                                     \
                _Pragma("unroll")                                                 \
                for (int g = 0; g < 4; ++g) acc[g] = (f32x4){0.f, 0.f, 0.f, 0.f}; \
                _Pragma("unroll")                                                 \
                for (int kk = 0; kk < 8; ++kk) {                                  \
                    s16x8 bfrag = *reinterpret_cast<const s16x8*>(                \
                        (BUF) + ((kk * 4 + kg) * 64 + f * 16 + rl) * 16);         \
                    _Pragma("unroll")                                             \
                    for (int g = 0; g < 4; ++g)                                   \
                        acc[g] = __builtin_amdgcn_mfma_f32_16x16x32_bf16(         \
                            afrag[g][kk], bfrag, acc[g], 0, 0, 0);                \
                }                                                                 \
                _Pragma("unroll")                                                 \
                for (int g = 0; g < 4; ++g)                                       \
                    _Pragma("unroll")                                             \
                    for (int r = 0; r < 4; ++r)                                   \
                        s_acc[g][r] += exp2f(fmaf(acc[g][r], C_2LOG2E, -C_2LOG2E)); \
            }                                                                     \
        }

    STAGE(lds[0], 0);
    __syncthreads();                       // drains vmcnt -> tile 0 ready
    for (int jt = 0; jt < 8; ++jt) {
        if (jt < 7) STAGE(lds[(jt + 1) & 1], jt + 1);
        COMPUTE(lds[jt & 1]);
        __syncthreads();                   // next tile landed; reads of cur done
    }

    // Sum over the 16 col-lanes (rl); rows i0 + g*16 + kg*4 + r.
    #pragma unroll
    for (int g = 0; g < 4; ++g)
        #pragma unroll
        for (int r = 0; r < 4; ++r) {
            float v = s_acc[g][r];
            #pragma unroll
            for (int off = 1; off < 16; off <<= 1) v += __shfl_xor(v, off, 64);
            if (rl == 0)
                partial[chunk * N_SZ + i0 + g * 16 + kg * 4 + r] = v;
        }
    #undef STAGE
    #undef COMPUTE
}

// ---- Kernel 3: per-row lse - pos, block partial sums (32 blocks x 256 rows) ----
__global__ __launch_bounds__(256) void rowsum_kernel(const float* __restrict__ partial,
                                                     const float* __restrict__ pos,
                                                     float* __restrict__ bpart) {
    const int row = blockIdx.x * 256 + threadIdx.x;
    float s = -1.0f;                       // remove diagonal exp(2-2)=1
    #pragma unroll
    for (int c = 0; c < 16; ++c) s += partial[c * N_SZ + row];
    float acc = 2.0f + logf(s) - pos[row];
    #pragma unroll
    for (int off = 32; off; off >>= 1) acc += __shfl_xor(acc, off, 64);
    __shared__ float w[4];
    if ((threadIdx.x & 63) == 0) w[threadIdx.x >> 6] = acc;
    __syncthreads();
    if (threadIdx.x == 0) bpart[blockIdx.x] = w[0] + w[1] + w[2] + w[3];
}

__global__ __launch_bounds__(64) void finsum_kernel(const float* __restrict__ bpart,
                                                    float* __restrict__ out) {
    float v = threadIdx.x < 32 ? bpart[threadIdx.x] : 0.0f;
    #pragma unroll
    for (int off = 32; off; off >>= 1) v += __shfl_xor(v, off, 64);
    if (threadIdx.x == 0) out[0] = v / (float)N_SZ;
}

extern "C" void kernel_launch(void* const* d_in, const int* in_sizes, int n_in,
                              void* d_out, int out_size, void* d_ws, size_t ws_size,
                              hipStream_t stream) {
    const float* zi = (const float*)d_in[0];
    const float* zj = (const float*)d_in[1];

    char* ws = (char*)d_ws;
    char* znb      = ws;                                   // 4 MB k-major bf16
    float* pos     = (float*)(ws + 4194304);               // 32 KB
    float* partial = (float*)(ws + 4194304 + 32768);       // 16*8192*4 = 512 KB
    float* bpart   = (float*)(ws + 4194304 + 32768 + 524288); // 128 B
    float* out = (float*)d_out;

    prep_kernel<<<B_SZ / 4, 256, 0, stream>>>(zi, zj, znb, pos);
    simlse_kernel<<<512, 256, 0, stream>>>(znb, partial);
    rowsum_kernel<<<32, 256, 0, stream>>>(partial, pos, bpart);
    finsum_kernel<<<1, 64, 0, stream>>>(bpart, out);
}